// Round 4
// baseline (215.608 us; speedup 1.0000x reference)
//
#include <hip/hip_runtime.h>
#include <cmath>

typedef __attribute__((ext_vector_type(8))) short short8;
typedef __attribute__((ext_vector_type(4))) short short4v;
typedef __attribute__((ext_vector_type(16))) float floatx16;
typedef __attribute__((ext_vector_type(4))) int int4v;
typedef unsigned short ushort_t;

#define LSEQ   2048
#define DMODEL 1024
#define BM 128
#define BN 128
#define BK 64
#define TPAD 136   // transpose LDS row stride (elems) for legacy qkv kernel

// log2(0.96875)
#define L2GAMMA (-0.045803595f)
// log2(10000)/512
#define L2E4_512 (0.0259525632f)

// float -> bf16 with round-to-nearest-even
__device__ __forceinline__ ushort_t f2b(float x) {
    union { float f; unsigned u; } v; v.f = x;
    unsigned r = v.u + 0x7fffu + ((v.u >> 16) & 1u);
    return (ushort_t)(r >> 16);
}

#define GLOAD_LDS16(gptr, lptr)                                                     \
    __builtin_amdgcn_global_load_lds(                                               \
        (const __attribute__((address_space(1))) unsigned int*)(gptr),              \
        (__attribute__((address_space(3))) unsigned int*)(lptr), 16, 0, 0)

// inline-asm ds_read_b128 with immediate offset (string literal), keeps the
// compiler's alias analysis away from the LDS-DMA destinations.
#define DSR(d, a, o) \
    asm volatile("ds_read_b128 %0, %1 offset:" o : "=v"(d) : "v"(a))

__device__ __forceinline__ short8 as_s8(int4v v) {
    return __builtin_bit_cast(short8, v);
}
#define MFMA_B16 __builtin_amdgcn_mfma_f32_32x32x16_bf16

// ---------------------------------------------------------------------------
// GEMM core (legacy 128x128 structure): used by score/av kernels (and the
// fallback qkv). C(128x128) += A[aRow0..][k] * B[bRow0..][k]^T, bf16 MFMA
// 32x32x16, BK=64, single LDS buffer pair, (row&7) XOR chunk swizzle.
// ---------------------------------------------------------------------------
__device__ __forceinline__ void gemm_core(
    const ushort_t* __restrict__ Ag, int lda, int aRow0,
    const ushort_t* __restrict__ Bg, int ldb, int bRow0,
    int kDepth, ushort_t* As, ushort_t* Bs, floatx16 acc[2][2])
{
    const int tid  = threadIdx.x;
    const int wave = tid >> 6, lane = tid & 63;
    const int wm = wave >> 1, wn = wave & 1;
    const int l31 = lane & 31, half = lane >> 5;
    const int srow = lane >> 3;                       // 0..7 within 8-row group
    const int scol = ((lane & 7) ^ srow) * 8;         // swizzled source chunk

    const ushort_t* ap[4];
    const ushort_t* bp[4];
    #pragma unroll
    for (int L = 0; L < 4; ++L) {
        int r = (wave * 4 + L) * 8 + srow;            // 0..127
        ap[L] = Ag + (size_t)(aRow0 + r) * lda + scol;
        bp[L] = Bg + (size_t)(bRow0 + r) * ldb + scol;
    }
    const int ldst = (lane >> 3) * BK + (lane & 7) * 8;

    for (int k0 = 0; k0 < kDepth; k0 += BK) {
        __syncthreads();
        #pragma unroll
        for (int L = 0; L < 4; ++L) {
            GLOAD_LDS16(ap[L], As + (wave * 4 + L) * (8 * BK) + ldst);
            GLOAD_LDS16(bp[L], Bs + (wave * 4 + L) * (8 * BK) + ldst);
            ap[L] += BK; bp[L] += BK;
        }
        __syncthreads();

        #pragma unroll
        for (int ks = 0; ks < 4; ++ks) {
            const int ch = ((ks * 2 + half) ^ (l31 & 7)) * 8;  // un-swizzle
            short8 a0 = *(const short8*)(As + (wm * 64      + l31) * BK + ch);
            short8 a1 = *(const short8*)(As + (wm * 64 + 32 + l31) * BK + ch);
            short8 b0 = *(const short8*)(Bs + (wn * 64      + l31) * BK + ch);
            short8 b1 = *(const short8*)(Bs + (wn * 64 + 32 + l31) * BK + ch);
            acc[0][0] = MFMA_B16(a0, b0, acc[0][0], 0, 0, 0);
            acc[0][1] = MFMA_B16(a0, b1, acc[0][1], 0, 0, 0);
            acc[1][0] = MFMA_B16(a1, b0, acc[1][0], 0, 0, 0);
            acc[1][1] = MFMA_B16(a1, b1, acc[1][1], 0, 0, 0);
        }
    }
}
// C/D layout 32x32x16: col = lane&31 (+ni*32), row = (reg&3) + 8*(reg>>2) +
// 4*(lane>>5) (+mi*32); reg = rg*4+q -> 4 consecutive rows per rg group.

// ---------------------------------------------------------------------------
// Prep: xpos (cos,sin) tables with xpos-scale AND decay gamma^{+-l} folded in.
// ---------------------------------------------------------------------------
__global__ __launch_bounds__(256) void xpos_table_kernel(float2* __restrict__ T)
{
    int idx = blockIdx.x * 256 + threadIdx.x;   // 2*512*2048 entries
    int l = idx & 2047;
    int p = (idx >> 11) & 511;
    int mode = idx >> 20;
    float sv = (2.0f * (float)p + 409.6f) * (1.0f / 1433.6f);
    float coeff = log2f(sv) * (1.0f / 512.0f) + L2GAMMA;
    float invf = exp2f(-(float)p * L2E4_512);
    float lf = (float)l;
    float s, c;
    sincosf(lf * invf, &s, &c);
    float g = exp2f((mode == 0 ? lf : -lf) * coeff);
    T[idx] = make_float2(c * g, s * g);
}

// ---------------------------------------------------------------------------
// Prep: fp32 -> bf16 cast of X
// ---------------------------------------------------------------------------
__global__ __launch_bounds__(256) void cast_x_kernel(
    const float4* __restrict__ X, short4v* __restrict__ Xb, int n4)
{
    int i = blockIdx.x * 256 + threadIdx.x;
    if (i < n4) {
        float4 v = X[i];
        short4v o;
        o.x = (short)f2b(v.x); o.y = (short)f2b(v.y);
        o.z = (short)f2b(v.z); o.w = (short)f2b(v.w);
        Xb[i] = o;
    }
}

// ---------------------------------------------------------------------------
// Prep: W (fp32 [K][N]) -> Wt (bf16 [N][K]) for all three weights
// ---------------------------------------------------------------------------
__global__ __launch_bounds__(256) void wtrans_kernel(
    const float* __restrict__ Wq, const float* __restrict__ Wk,
    const float* __restrict__ Wv, ushort_t* __restrict__ Wt)
{
    const float* W = blockIdx.z == 0 ? Wq : blockIdx.z == 1 ? Wk : Wv;
    ushort_t* O = Wt + (size_t)blockIdx.z * (DMODEL * DMODEL);
    __shared__ float t[32][33];
    const int x = threadIdx.x & 31, y = (threadIdx.x >> 5) * 4;
    const int k0 = blockIdx.y * 32, n0 = blockIdx.x * 32;
    #pragma unroll
    for (int j = 0; j < 4; ++j)
        t[y + j][x] = W[(size_t)(k0 + y + j) * DMODEL + n0 + x];
    __syncthreads();
    #pragma unroll
    for (int j = 0; j < 4; ++j)
        O[(size_t)(n0 + y + j) * DMODEL + k0 + x] = f2b(t[x][y + j]);
}

// ---------------------------------------------------------------------------
// Legacy Stage 1 (fallback only, if 128 KiB dynamic LDS is unavailable).
// ---------------------------------------------------------------------------
__global__ __launch_bounds__(256, 4) void qkv_kernel(
    const ushort_t* __restrict__ Xb, const ushort_t* __restrict__ Wt,
    const float2* __restrict__ Tab,
    ushort_t* __restrict__ Q, ushort_t* __restrict__ Ko, ushort_t* __restrict__ Vt)
{
    __shared__ ushort_t smem[128 * TPAD];
    ushort_t* As = smem;
    ushort_t* Bs = smem + BM * BK;

    const int lin = blockIdx.x;
    const int inner = lin & 63;
    const int sup = lin >> 6;
    const int c = (sup % 3) * 8 + (inner & 7);
    const int r = (sup / 3) * 8 + (inner >> 3);
    const int mode = c >> 3;
    const int c0 = (c & 7) * BN;
    const int row0 = r * BM;

    floatx16 acc[2][2] = {};
    gemm_core(Xb, DMODEL, row0,
              Wt + (size_t)mode * (DMODEL * DMODEL), DMODEL, c0,
              DMODEL, As, Bs, acc);

    const int wave = threadIdx.x >> 6, lane = threadIdx.x & 63;
    const int wm = wave >> 1, wn = wave & 1;
    const int l31 = lane & 31, half = lane >> 5;
    const int rBase = row0 + wm * 64 + 4 * half;
    const int cBase = c0 + wn * 64 + l31;

    if (mode == 2) {
        const int colL0 = wn * 64 + l31;
        const int rowL0 = wm * 64 + 4 * half;
        __syncthreads();
        #pragma unroll
        for (int mi = 0; mi < 2; ++mi)
            #pragma unroll
            for (int ni = 0; ni < 2; ++ni)
                #pragma unroll
                for (int rg = 0; rg < 4; ++rg) {
                    short4v pk;
                    pk.x = (short)f2b(acc[mi][ni][rg * 4 + 0]);
                    pk.y = (short)f2b(acc[mi][ni][rg * 4 + 1]);
                    pk.z = (short)f2b(acc[mi][ni][rg * 4 + 2]);
                    pk.w = (short)f2b(acc[mi][ni][rg * 4 + 3]);
                    *(short4v*)(smem + (colL0 + ni * 32) * TPAD
                                     + rowL0 + mi * 32 + 8 * rg) = pk;
                }
        __syncthreads();
        const int t = threadIdx.x;
        const int colV = c0 + (t >> 1);
        const int lhalf = (t & 1) * 64;
        const int b = row0 >> 11, lpos0 = (row0 & 2047) + lhalf;
        #pragma unroll
        for (int i = 0; i < 8; ++i) {
            short8 vv = *(const short8*)(smem + (t >> 1) * TPAD + lhalf + i * 8);
            *(short8*)(Vt + (size_t)b * (LSEQ * DMODEL)
                          + (size_t)colV * LSEQ + lpos0 + i * 8) = vv;
        }
    } else {
        ushort_t* O = (mode == 0) ? Q : Ko;
        const float2* Tm = Tab + (size_t)mode * (512 * 2048);
        #pragma unroll
        for (int ni = 0; ni < 2; ++ni) {
            int col = cBase + ni * 32;
            const float2* tp = Tm + ((size_t)(col >> 1) << 11);
            #pragma unroll
            for (int mi = 0; mi < 2; ++mi)
                #pragma unroll
                for (int rg = 0; rg < 4; ++rg) {
                    int l0 = (rBase + mi * 32 + 8 * rg) & 2047;
                    float4 t01 = *(const float4*)(tp + l0);
                    float4 t23 = *(const float4*)(tp + l0 + 2);
                    float cs[8] = {t01.x, t01.y, t01.z, t01.w,
                                   t23.x, t23.y, t23.z, t23.w};
                    #pragma unroll
                    for (int q = 0; q < 4; ++q) {
                        int row = rBase + mi * 32 + 8 * rg + q;
                        float cc = cs[2 * q], ss = cs[2 * q + 1];
                        float v  = acc[mi][ni][rg * 4 + q];
                        float pv = __shfl_xor(v, 1);
                        float res = (lane & 1) ? fmaf(v, cc, pv * ss)
                                               : fmaf(v, cc, -pv * ss);
                        O[(size_t)row * DMODEL + col] = f2b(res);
                    }
                }
        }
    }
}

// ---------------------------------------------------------------------------
// Stage 1: 256x256 tile, 512 threads (8 waves, 2M x 4N), BK=64, double-
// buffered 128 KiB LDS, pipelined phases, counted vmcnt(2).
//
// v4 (de-lockstepped): only TWO block barriers per K-tile.
//   (1) phase-3 entry barrier: guards staging A0(j+2) into the CURRENT buf's
//       A region -- every wave's reads of that region (a01 @ p0, a23 @ p2)
//       are drained by its own lgkmcnt(0) before it arrives.
//   (2) tile-end barrier (after per-wave vmcnt(2)): guards buf nb's 8 loads
//       (issued by all waves in p0-p1 + prev p3) before j+1 reads them.
//   All p0-p1 stages target buf nb, whose last reads (iter j-1) drained
//   before the PREVIOUS phase-3 barrier -> no intra-phase barriers needed.
//   Waves drift across phases 0-2: leading waves' MFMA overlaps trailing
//   waves' ds_reads -> LDS pipe and MFMA pipe busy simultaneously.
//
// Ledger (per wave, per iter): enter with A0(j+1) in flight (2).
// p0 +A1(j+1),B0(j+1) (4) -> 6; p1 +B1(j+1) (2) -> 8; p3 +A0(j+2) (2) -> 10;
// vmcnt(2) retires the 8 loads of K-tile j+1, leaves A0(j+2).
// Trailing iters stage slightly-OOB columns (still inside d_ws; data never
// consumed; drained by final vmcnt(0)).
// ---------------------------------------------------------------------------
__global__ __launch_bounds__(512, 2) void qkv256_kernel(
    const ushort_t* __restrict__ Xb, const ushort_t* __restrict__ Wt,
    const float2* __restrict__ Tab,
    ushort_t* __restrict__ Q, ushort_t* __restrict__ Ko, ushort_t* __restrict__ Vt)
{
    extern __shared__ ushort_t smem[];   // 131072 B
    // byte map: A: buf*32768 + h*16384 ; B: 65536 + buf*32768 + h*16384
    const int tid  = threadIdx.x;
    const int wave = tid >> 6, lane = tid & 63;
    const int wm = wave >> 2, wn = wave & 3;        // 2 x 4 wave grid
    const int l31 = lane & 31, half = lane >> 5;
    const int xl  = l31 & 7;

    // block decode: XCD-bijective swizzle (grid % 8 == 0) + 4x4 supertile
    const int nwg = gridDim.x;
    const int cpx = nwg >> 3;
    const int orig = blockIdx.x;
    const int wg = (orig & 7) * cpx + (orig >> 3);
    const int sup = wg >> 4, inner = wg & 15;
    const int ct = (sup % 3) * 4 + (inner & 3);     // 0..11  (mode = ct>>2)
    const int rt = (sup / 3) * 4 + (inner >> 2);    // row tile
    const int mode = ct >> 2;
    const int row0 = rt << 8;
    const int c0m  = (ct & 3) << 8;                 // col within mode

    const char* gA = (const char*)Xb;                                   // SGPR
    const char* gB = (const char*)(Wt + (size_t)mode * (DMODEL * DMODEL));

    // staging voffsets (bytes): 8 rows per wave, swizzled 16B chunk in row
    const int t8 = tid >> 3;
    const int scol = (((tid & 7) ^ (t8 & 7)) << 3);
    unsigned oA0  = (unsigned)(((row0 + t8) * DMODEL + scol) * 2);
    unsigned oA0b = oA0 + 64  * DMODEL * 2;
    unsigned oA1  = oA0 + 128 * DMODEL * 2;
    unsigned oA1b = oA0 + 192 * DMODEL * 2;
    unsigned oB0  = (unsigned)(((c0m + t8) * DMODEL + scol) * 2);
    unsigned oB0b = oB0 + 64  * DMODEL * 2;
    unsigned oB1  = oB0 + 128 * DMODEL * 2;
    unsigned oB1b = oB0 + 192 * DMODEL * 2;

    char* ldsT = (char*)smem + tid * 16;   // HW uses wave-uniform base + lane*16
    int stg = 0;                           // buf bit for staging (byte offset)

    // ds_read byte addresses (persistent VGPRs, buffer bit toggled ^=32768)
    int vaA[4], vaB[4];
    #pragma unroll
    for (int ks = 0; ks < 4; ++ks) {
        const int swz = (((ks * 2 + half) ^ xl) << 4);
        vaA[ks] = wm * 16384 + l31 * 128 + swz;
        vaB[ks] = 65536 + (wn >> 1) * 16384 + ((wn & 1) * 64 + l31) * 128 + swz;
    }

    // prologue: K-tile 0 (all 4 half-tiles) + A0 of K-tile 1
    GLOAD_LDS16(gA + oA0,  ldsT);                  GLOAD_LDS16(gA + oA0b, ldsT + 8192);
    GLOAD_LDS16(gA + oA1,  ldsT + 16384);          GLOAD_LDS16(gA + oA1b, ldsT + 16384 + 8192);
    GLOAD_LDS16(gB + oB0,  ldsT + 65536);          GLOAD_LDS16(gB + oB0b, ldsT + 65536 + 8192);
    GLOAD_LDS16(gB + oB1,  ldsT + 65536 + 16384);  GLOAD_LDS16(gB + oB1b, ldsT + 65536 + 16384 + 8192);
    oA0 += 128; oA0b += 128; oA1 += 128; oA1b += 128;
    oB0 += 128; oB0b += 128; oB1 += 128; oB1b += 128;
    GLOAD_LDS16(gA + oA0, ldsT + 32768);           GLOAD_LDS16(gA + oA0b, ldsT + 32768 + 8192);
    oA0 += 128; oA0b += 128;
    asm volatile("s_waitcnt vmcnt(2)" ::: "memory");
    __builtin_amdgcn_s_barrier();

    floatx16 acc[4][2] = {};
    int4v a0[2][4], a2[2][4], b0[4], b1[4];

    for (int j = 0; j < 16; ++j) {
        const int nstg = stg ^ 32768;

        // ---- phase 0: read a01 + b0; stage A1(j+1) + B0(j+1); mfma a01 x b0
        #pragma unroll
        for (int ks = 0; ks < 4; ++ks) {
            DSR(a0[0][ks], vaA[ks], "0");
            DSR(a0[1][ks], vaA[ks], "4096");
            DSR(b0[ks],    vaB[ks], "0");
        }
        GLOAD_LDS16(gA + oA1,  ldsT + nstg + 16384);
        GLOAD_LDS16(gA + oA1b, ldsT + nstg + 16384 + 8192);
        oA1 += 128; oA1b += 128;
        GLOAD_LDS16(gB + oB0,  ldsT + nstg + 65536);
        GLOAD_LDS16(gB + oB0b, ldsT + nstg + 65536 + 8192);
        oB0 += 128; oB0b += 128;
        asm volatile("s_waitcnt lgkmcnt(0)" ::: "memory");
        __builtin_amdgcn_sched_barrier(0);
        __builtin_amdgcn_s_setprio(1);
        #pragma unroll
        for (int ks = 0; ks < 4; ++ks) {
            acc[0][0] = MFMA_B16(as_s8(a0[0][ks]), as_s8(b0[ks]), acc[0][0], 0, 0, 0);
            acc[1][0] = MFMA_B16(as_s8(a0[1][ks]), as_s8(b0[ks]), acc[1][0], 0, 0, 0);
        }
        __builtin_amdgcn_s_setprio(0);

        // ---- phase 1: read b1; stage B1(j+1); mfma a01 x b1 (a01 dies)
        #pragma unroll
        for (int ks = 0; ks < 4; ++ks)
            DSR(b1[ks], vaB[ks], "4096");
        GLOAD_LDS16(gB + oB1,  ldsT + nstg + 65536 + 16384);
        GLOAD_LDS16(gB + oB1b, ldsT + nstg + 65536 + 16384 + 8192);
        oB1 += 128; oB1b += 128;
        asm volatile("s_waitcnt lgkmcnt(0)" ::: "memory");
        __builtin_amdgcn_sched_barrier(0);
        __builtin_amdgcn_s_setprio(1);
        #pragma unroll
        for (int ks = 0; ks < 4; ++ks) {
            acc[0][1] = MFMA_B16(as_s8(a0[0][ks]), as_s8(b1[ks]), acc[0][1], 0, 0, 0);
            acc[1][1] = MFMA_B16(as_s8(a0[1][ks]), as_s8(b1[ks]), acc[1][1], 0, 0, 0);
        }
        __builtin_amdgcn_s_setprio(0);

        // ---- phase 2: read a23; mfma a23 x b0 (b0 dies)
        #pragma unroll
        for (int ks = 0; ks < 4; ++ks) {
            DSR(a2[0][ks], vaA[ks], "8192");
            DSR(a2[1][ks], vaA[ks], "12288");
        }
        asm volatile("s_waitcnt lgkmcnt(0)" ::: "memory");
        __builtin_amdgcn_sched_barrier(0);
        __builtin_amdgcn_s_setprio(1);
        #pragma unroll
        for (int ks = 0; ks < 4; ++ks) {
            acc[2][0] = MFMA_B16(as_s8(a2[0][ks]), as_s8(b0[ks]), acc[2][0], 0, 0, 0);
            acc[3][0] = MFMA_B16(as_s8(a2[1][ks]), as_s8(b0[ks]), acc[3][0], 0, 0, 0);
        }
        __builtin_amdgcn_s_setprio(0);

        // ---- phase-3 entry barrier: all waves' reads of CURRENT buf's A
        //      region are drained (own lgkmcnt above) -> safe to overwrite.
        __builtin_amdgcn_s_barrier();

        // ---- phase 3: stage A0(j+2) into CURRENT buf; mfma a23 x b1;
        //      single counted vmcnt per K-tile (retires all of j+1's loads)
        GLOAD_LDS16(gA + oA0,  ldsT + stg);
        GLOAD_LDS16(gA + oA0b, ldsT + stg + 8192);
        oA0 += 128; oA0b += 128;
        __builtin_amdgcn_s_setprio(1);
        #pragma unroll
        for (int ks = 0; ks < 4; ++ks) {
            acc[2][1] = MFMA_B16(as_s8(a2[0][ks]), as_s8(b1[ks]), acc[2][1], 0, 0, 0);
            acc[3][1] = MFMA_B16(as_s8(a2[1][ks]), as_s8(b1[ks]), acc[3][1], 0, 0, 0);
        }
        __builtin_amdgcn_s_setprio(0);
        asm volatile("s_waitcnt vmcnt(2)" ::: "memory");
        __builtin_amdgcn_s_barrier();

        stg ^= 32768;
        #pragma unroll
        for (int ks = 0; ks < 4; ++ks) { vaA[ks] ^= 32768; vaB[ks] ^= 32768; }
    }

    // ------------------------- epilogue -------------------------
    const int rB = row0 + wm * 128 + 4 * half;   // + m*32 + 8*rg + q
    const int cB = c0m + wn * 64 + l31;          // + n*32

    if (mode < 2) {
        ushort_t* O = (mode == 0) ? Q : Ko;
        const float2* Tm = Tab + (size_t)mode * (512 * 2048);
        #pragma unroll
        for (int n = 0; n < 2; ++n) {
            const int col = cB + n * 32;
            const float2* tp = Tm + ((size_t)(col >> 1) << 11);
            #pragma unroll
            for (int m = 0; m < 4; ++m)
                #pragma unroll
                for (int rg = 0; rg < 4; ++rg) {
                    const int row = rB + m * 32 + 8 * rg;
                    const int l0 = row & 2047;
                    float4 t01 = *(const float4*)(tp + l0);
                    float4 t23 = *(const float4*)(tp + l0 + 2);
                    float cs[8] = {t01.x, t01.y, t01.z, t01.w,
                                   t23.x, t23.y, t23.z, t23.w};
                    #pragma unroll
                    for (int q = 0; q < 4; ++q) {
                        float v  = acc[m][n][rg * 4 + q];
                        float pv = __shfl_xor(v, 1);
                        float cc = cs[2 * q], ss = cs[2 * q + 1];
                        float res = (lane & 1) ? fmaf(v, cc, pv * ss)
                                               : fmaf(v, cc, -pv * ss);
                        O[(size_t)(row + q) * DMODEL + col] = f2b(res);
                    }
                }
        }
    } else {
        // V: transpose 256x256 tile via LDS in two 128-col passes
        __syncthreads();   // drains outstanding staging; staging buffers dead
        const int bidx = row0 >> 11, lpos0 = row0 & 2047;
        #pragma unroll
        for (int ph = 0; ph < 2; ++ph) {
            if ((wn >> 1) == ph) {
                const int colL = (wn & 1) * 64 + l31;   // + n*32 -> 0..127
                const int rowL = wm * 128 + 4 * half;   // + m*32 + 8*rg
                #pragma unroll
                for (int m = 0; m < 4; ++m)
                    #pragma unroll
                    for (int n = 0; n < 2; ++n)
                        #pragma unroll
                        for (int rg = 0; rg < 4; ++rg) {
                            short4v pk;
                            pk.x = (short)f2b(acc[m][n][rg * 4 + 0]);
                            pk.y = (short)f2b(acc[m][n][rg * 4 + 1]);
                            pk.z = (short)f2b(acc[m][n][rg * 4 + 2]);
                            pk.w = (short)f2b(acc[m][n][rg * 4 + 3]);
                            *(short4v*)(smem + (size_t)(colL + n * 32) * 264
                                             + rowL + m * 32 + 8 * rg) = pk;
                        }
            }
            __syncthreads();
            const int colV = c0m + ph * 128 + (tid >> 2);
            const int qtr  = tid & 3;
            #pragma unroll
            for (int i = 0; i < 8; ++i) {
                short8 vv = *(const short8*)(smem + (size_t)(tid >> 2) * 264
                                                  + qtr * 64 + i * 8);
                *(short8*)(Vt + (size_t)bidx * (LSEQ * DMODEL)
                              + (size_t)colV * LSEQ + lpos0 + qtr * 64 + i * 8) = vv;
            }
            __syncthreads();
        }
    }
    // drain the trailing staging loads before endpgm (LDS DMA safety)
    asm volatile("s_waitcnt vmcnt(0)" ::: "memory");
}

// ---------------------------------------------------------------------------
// Stage 2: S = Q-hat . K-hat^T (decay pre-folded), banded: only tiles with
// bi-2 <= bj <= bi. 45 tiles per batch.
// ---------------------------------------------------------------------------
__global__ __launch_bounds__(256, 4) void score_kernel(
    const ushort_t* __restrict__ Q, const ushort_t* __restrict__ Kc,
    ushort_t* __restrict__ S)
{
    const int t = blockIdx.x, z = blockIdx.z;
    int bi, bj;
    if (t < 3) { bi = (t > 0); bj = t - (t > 0); }
    else { int u = t - 3; bi = 2 + u / 3; bj = bi - 2 + u % 3; }

    __shared__ ushort_t As[BM * BK], Bs[BN * BK];
    floatx16 acc[2][2] = {};
    const size_t zoff = (size_t)z * (LSEQ * DMODEL);
    gemm_core(Q + zoff, DMODEL, bi * BM, Kc + zoff, DMODEL, bj * BN,
              DMODEL, As, Bs, acc);

    const int wave = threadIdx.x >> 6, lane = threadIdx.x & 63;
    const int wm = wave >> 1, wn = wave & 1;
    const int l31 = lane & 31, half = lane >> 5;
    const int nBase = bi * BM + wm * 64 + 4 * half;
    const int mBase = bj * BN + wn * 64 + l31;
    ushort_t* Sz = S + (size_t)z * LSEQ * LSEQ;
    #pragma unroll
    for (int mi = 0; mi < 2; ++mi)
        #pragma unroll
        for (int ni = 0; ni < 2; ++ni) {
            int m = mBase + ni * 32;
            #pragma unroll
            for (int rg = 0; rg < 4; ++rg)
                #pragma unroll
                for (int q = 0; q < 4; ++q) {
                    int n = nBase + mi * 32 + 8 * rg + q;
                    Sz[(size_t)n * LSEQ + m] =
                        (m <= n) ? f2b(acc[mi][ni][rg * 4 + q]) : (ushort_t)0;
                }
        }
}

// ---------------------------------------------------------------------------
// Stage 3: O = S @ V, banded k-window [max(0,(bi-2)*128), (bi+1)*128).
// ---------------------------------------------------------------------------
__global__ __launch_bounds__(256, 4) void av_kernel(
    const ushort_t* __restrict__ S, const ushort_t* __restrict__ Vt,
    float* __restrict__ Out)
{
    const int bx = blockIdx.x, bi = blockIdx.y, z = blockIdx.z;
    const int kLo = (bi >= 2) ? (bi - 2) * BM : 0;
    const int kW  = (bi + 1) * BM - kLo;
    __shared__ ushort_t As[BM * BK], Bs[BN * BK];
    floatx16 acc[2][2] = {};
    gemm_core(S + (size_t)z * LSEQ * LSEQ + kLo, LSEQ, bi * BM,
              Vt + (size_t)z * (LSEQ * DMODEL) + kLo, LSEQ, bx * BN,
              kW, As, Bs, acc);

    const int wave = threadIdx.x >> 6, lane = threadIdx.x & 63;
    const int wm = wave >> 1, wn = wave & 1;
    const int l31 = lane & 31, half = lane >> 5;
    const int rBase = bi * BM + wm * 64 + 4 * half;
    const int cBase = bx * BN + wn * 64 + l31;
    float* Oz = Out + (size_t)z * (LSEQ * DMODEL);
    #pragma unroll
    for (int mi = 0; mi < 2; ++mi)
        #pragma unroll
        for (int ni = 0; ni < 2; ++ni)
            #pragma unroll
            for (int rg = 0; rg < 4; ++rg)
                #pragma unroll
                for (int q = 0; q < 4; ++q)
                    Oz[(size_t)(rBase + mi * 32 + 8 * rg + q) * DMODEL
                       + cBase + ni * 32] = acc[mi][ni][rg * 4 + q];
}

// ---------------------------------------------------------------------------
extern "C" void kernel_launch(void* const* d_in, const int* in_sizes, int n_in,
                              void* d_out, int out_size, void* d_ws, size_t ws_size,
                              hipStream_t stream)
{
    const float* X  = (const float*)d_in[0];
    const float* Wq = (const float*)d_in[1];
    const float* Wk = (const float*)d_in[2];
    const float* Wv = (const float*)d_in[3];
    float* out = (float*)d_out;

    const size_t LH  = (size_t)LSEQ * DMODEL;
    const size_t WSZ = (size_t)DMODEL * DMODEL;
    const size_t SSZ = (size_t)LSEQ * LSEQ;
    const size_t TABN = (size_t)2 * 512 * 2048;

    size_t need4 = TABN * 8 + 2 * (3 * WSZ + 4 * (4 * LH + SSZ));
    const int bs = (ws_size >= need4) ? 4 : 1;

    float2* Tab = (float2*)d_ws;
    ushort_t* ws16 = (ushort_t*)(Tab + TABN);
    ushort_t* Wt = ws16;
    ushort_t* Xb = Wt + 3 * WSZ;
    ushort_t* Q  = Xb + (size_t)bs * LH;
    ushort_t* Kb = Q  + (size_t)bs * LH;
    ushort_t* Vt = Kb + (size_t)bs * LH;
    ushort_t* S  = Vt + (size_t)bs * LH;

    // one-time: allow 128 KiB dynamic LDS for the pipelined QKV kernel
    static int qkv256_ok = -1;
    if (qkv256_ok < 0) {
        hipError_t e = hipFuncSetAttribute(
            reinterpret_cast<const void*>(qkv256_kernel),
            hipFuncAttributeMaxDynamicSharedMemorySize, 131072);
        qkv256_ok = (e == hipSuccess) ? 1 : 0;
    }

    xpos_table_kernel<<<dim3(TABN / 256), 256, 0, stream>>>(Tab);
    wtrans_kernel<<<dim3(32, 32, 3), 256, 0, stream>>>(Wq, Wk, Wv, Wt);

    for (int p = 0; p < 4 / bs; ++p) {
        const float* Xp = X + (size_t)p * bs * LH;
        cast_x_kernel<<<dim3(bs * 2048), 256, 0, stream>>>(
            (const float4*)Xp, (short4v*)Xb, bs * (int)(LH / 4));
        if (qkv256_ok)
            qkv256_kernel<<<dim3(96 * bs), 512, 131072, stream>>>(
                Xb, Wt, Tab, Q, Kb, Vt);
        else
            qkv_kernel<<<dim3(24 * bs * 16), 256, 0, stream>>>(
                Xb, Wt, Tab, Q, Kb, Vt);
        score_kernel<<<dim3(45, 1, bs), 256, 0, stream>>>(Q, Kb, S);
        av_kernel<<<dim3(8, 16, bs), 256, 0, stream>>>(S, Vt,
            out + (size_t)p * bs * LH);
    }
}

// Round 5
// 208.219 us; speedup vs baseline: 1.0355x; 1.0355x over previous
//
#include <hip/hip_runtime.h>
#include <cmath>

typedef __attribute__((ext_vector_type(8))) short short8;
typedef __attribute__((ext_vector_type(4))) short short4v;
typedef __attribute__((ext_vector_type(16))) float floatx16;
typedef __attribute__((ext_vector_type(4))) int int4v;
typedef unsigned short ushort_t;

#define LSEQ   2048
#define DMODEL 1024
#define BM 128
#define BN 128
#define BK 64
#define TPAD 136   // transpose LDS row stride (elems) for legacy qkv kernel

// log2(0.96875)
#define L2GAMMA (-0.045803595f)
// log2(10000)/512
#define L2E4_512 (0.0259525632f)

// float -> bf16 with round-to-nearest-even
__device__ __forceinline__ ushort_t f2b(float x) {
    union { float f; unsigned u; } v; v.f = x;
    unsigned r = v.u + 0x7fffu + ((v.u >> 16) & 1u);
    return (ushort_t)(r >> 16);
}

#define GLOAD_LDS16(gptr, lptr)                                                     \
    __builtin_amdgcn_global_load_lds(                                               \
        (const __attribute__((address_space(1))) unsigned int*)(gptr),              \
        (__attribute__((address_space(3))) unsigned int*)(lptr), 16, 0, 0)

// inline-asm ds_read_b128 with immediate offset (string literal), keeps the
// compiler's alias analysis away from the LDS-DMA destinations.
#define DSR(d, a, o) \
    asm volatile("ds_read_b128 %0, %1 offset:" o : "=v"(d) : "v"(a))

__device__ __forceinline__ short8 as_s8(int4v v) {
    return __builtin_bit_cast(short8, v);
}
#define MFMA_B16 __builtin_amdgcn_mfma_f32_32x32x16_bf16

// ---------------------------------------------------------------------------
// GEMM core (legacy 128x128 structure): used by score/av kernels (and the
// fallback qkv). C(128x128) += A[aRow0..][k] * B[bRow0..][k]^T, bf16 MFMA
// 32x32x16, BK=64, single LDS buffer pair, (row&7) XOR chunk swizzle.
// ---------------------------------------------------------------------------
__device__ __forceinline__ void gemm_core(
    const ushort_t* __restrict__ Ag, int lda, int aRow0,
    const ushort_t* __restrict__ Bg, int ldb, int bRow0,
    int kDepth, ushort_t* As, ushort_t* Bs, floatx16 acc[2][2])
{
    const int tid  = threadIdx.x;
    const int wave = tid >> 6, lane = tid & 63;
    const int wm = wave >> 1, wn = wave & 1;
    const int l31 = lane & 31, half = lane >> 5;
    const int srow = lane >> 3;                       // 0..7 within 8-row group
    const int scol = ((lane & 7) ^ srow) * 8;         // swizzled source chunk

    const ushort_t* ap[4];
    const ushort_t* bp[4];
    #pragma unroll
    for (int L = 0; L < 4; ++L) {
        int r = (wave * 4 + L) * 8 + srow;            // 0..127
        ap[L] = Ag + (size_t)(aRow0 + r) * lda + scol;
        bp[L] = Bg + (size_t)(bRow0 + r) * ldb + scol;
    }
    const int ldst = (lane >> 3) * BK + (lane & 7) * 8;

    for (int k0 = 0; k0 < kDepth; k0 += BK) {
        __syncthreads();
        #pragma unroll
        for (int L = 0; L < 4; ++L) {
            GLOAD_LDS16(ap[L], As + (wave * 4 + L) * (8 * BK) + ldst);
            GLOAD_LDS16(bp[L], Bs + (wave * 4 + L) * (8 * BK) + ldst);
            ap[L] += BK; bp[L] += BK;
        }
        __syncthreads();

        #pragma unroll
        for (int ks = 0; ks < 4; ++ks) {
            const int ch = ((ks * 2 + half) ^ (l31 & 7)) * 8;  // un-swizzle
            short8 a0 = *(const short8*)(As + (wm * 64      + l31) * BK + ch);
            short8 a1 = *(const short8*)(As + (wm * 64 + 32 + l31) * BK + ch);
            short8 b0 = *(const short8*)(Bs + (wn * 64      + l31) * BK + ch);
            short8 b1 = *(const short8*)(Bs + (wn * 64 + 32 + l31) * BK + ch);
            acc[0][0] = MFMA_B16(a0, b0, acc[0][0], 0, 0, 0);
            acc[0][1] = MFMA_B16(a0, b1, acc[0][1], 0, 0, 0);
            acc[1][0] = MFMA_B16(a1, b0, acc[1][0], 0, 0, 0);
            acc[1][1] = MFMA_B16(a1, b1, acc[1][1], 0, 0, 0);
        }
    }
}
// C/D layout 32x32x16: col = lane&31 (+ni*32), row = (reg&3) + 8*(reg>>2) +
// 4*(lane>>5) (+mi*32); reg = rg*4+q -> 4 consecutive rows per rg group.

// ---------------------------------------------------------------------------
// Prep: xpos (cos,sin) tables with xpos-scale AND decay gamma^{+-l} folded in.
// ---------------------------------------------------------------------------
__global__ __launch_bounds__(256) void xpos_table_kernel(float2* __restrict__ T)
{
    int idx = blockIdx.x * 256 + threadIdx.x;   // 2*512*2048 entries
    int l = idx & 2047;
    int p = (idx >> 11) & 511;
    int mode = idx >> 20;
    float sv = (2.0f * (float)p + 409.6f) * (1.0f / 1433.6f);
    float coeff = log2f(sv) * (1.0f / 512.0f) + L2GAMMA;
    float invf = exp2f(-(float)p * L2E4_512);
    float lf = (float)l;
    float s, c;
    sincosf(lf * invf, &s, &c);
    float g = exp2f((mode == 0 ? lf : -lf) * coeff);
    T[idx] = make_float2(c * g, s * g);
}

// ---------------------------------------------------------------------------
// Prep: fp32 -> bf16 cast of X
// ---------------------------------------------------------------------------
__global__ __launch_bounds__(256) void cast_x_kernel(
    const float4* __restrict__ X, short4v* __restrict__ Xb, int n4)
{
    int i = blockIdx.x * 256 + threadIdx.x;
    if (i < n4) {
        float4 v = X[i];
        short4v o;
        o.x = (short)f2b(v.x); o.y = (short)f2b(v.y);
        o.z = (short)f2b(v.z); o.w = (short)f2b(v.w);
        Xb[i] = o;
    }
}

// ---------------------------------------------------------------------------
// Prep: W (fp32 [K][N]) -> Wt (bf16 [N][K]) for all three weights
// ---------------------------------------------------------------------------
__global__ __launch_bounds__(256) void wtrans_kernel(
    const float* __restrict__ Wq, const float* __restrict__ Wk,
    const float* __restrict__ Wv, ushort_t* __restrict__ Wt)
{
    const float* W = blockIdx.z == 0 ? Wq : blockIdx.z == 1 ? Wk : Wv;
    ushort_t* O = Wt + (size_t)blockIdx.z * (DMODEL * DMODEL);
    __shared__ float t[32][33];
    const int x = threadIdx.x & 31, y = (threadIdx.x >> 5) * 4;
    const int k0 = blockIdx.y * 32, n0 = blockIdx.x * 32;
    #pragma unroll
    for (int j = 0; j < 4; ++j)
        t[y + j][x] = W[(size_t)(k0 + y + j) * DMODEL + n0 + x];
    __syncthreads();
    #pragma unroll
    for (int j = 0; j < 4; ++j)
        O[(size_t)(n0 + y + j) * DMODEL + k0 + x] = f2b(t[x][y + j]);
}

// ---------------------------------------------------------------------------
// Legacy Stage 1 (fallback only, if 128 KiB dynamic LDS is unavailable).
// ---------------------------------------------------------------------------
__global__ __launch_bounds__(256, 4) void qkv_kernel(
    const ushort_t* __restrict__ Xb, const ushort_t* __restrict__ Wt,
    const float2* __restrict__ Tab,
    ushort_t* __restrict__ Q, ushort_t* __restrict__ Ko, ushort_t* __restrict__ Vt)
{
    __shared__ ushort_t smem[128 * TPAD];
    ushort_t* As = smem;
    ushort_t* Bs = smem + BM * BK;

    const int lin = blockIdx.x;
    const int inner = lin & 63;
    const int sup = lin >> 6;
    const int c = (sup % 3) * 8 + (inner & 7);
    const int r = (sup / 3) * 8 + (inner >> 3);
    const int mode = c >> 3;
    const int c0 = (c & 7) * BN;
    const int row0 = r * BM;

    floatx16 acc[2][2] = {};
    gemm_core(Xb, DMODEL, row0,
              Wt + (size_t)mode * (DMODEL * DMODEL), DMODEL, c0,
              DMODEL, As, Bs, acc);

    const int wave = threadIdx.x >> 6, lane = threadIdx.x & 63;
    const int wm = wave >> 1, wn = wave & 1;
    const int l31 = lane & 31, half = lane >> 5;
    const int rBase = row0 + wm * 64 + 4 * half;
    const int cBase = c0 + wn * 64 + l31;

    if (mode == 2) {
        const int colL0 = wn * 64 + l31;
        const int rowL0 = wm * 64 + 4 * half;
        __syncthreads();
        #pragma unroll
        for (int mi = 0; mi < 2; ++mi)
            #pragma unroll
            for (int ni = 0; ni < 2; ++ni)
                #pragma unroll
                for (int rg = 0; rg < 4; ++rg) {
                    short4v pk;
                    pk.x = (short)f2b(acc[mi][ni][rg * 4 + 0]);
                    pk.y = (short)f2b(acc[mi][ni][rg * 4 + 1]);
                    pk.z = (short)f2b(acc[mi][ni][rg * 4 + 2]);
                    pk.w = (short)f2b(acc[mi][ni][rg * 4 + 3]);
                    *(short4v*)(smem + (colL0 + ni * 32) * TPAD
                                     + rowL0 + mi * 32 + 8 * rg) = pk;
                }
        __syncthreads();
        const int t = threadIdx.x;
        const int colV = c0 + (t >> 1);
        const int lhalf = (t & 1) * 64;
        const int b = row0 >> 11, lpos0 = (row0 & 2047) + lhalf;
        #pragma unroll
        for (int i = 0; i < 8; ++i) {
            short8 vv = *(const short8*)(smem + (t >> 1) * TPAD + lhalf + i * 8);
            *(short8*)(Vt + (size_t)b * (LSEQ * DMODEL)
                          + (size_t)colV * LSEQ + lpos0 + i * 8) = vv;
        }
    } else {
        ushort_t* O = (mode == 0) ? Q : Ko;
        const float2* Tm = Tab + (size_t)mode * (512 * 2048);
        #pragma unroll
        for (int ni = 0; ni < 2; ++ni) {
            int col = cBase + ni * 32;
            const float2* tp = Tm + ((size_t)(col >> 1) << 11);
            #pragma unroll
            for (int mi = 0; mi < 2; ++mi)
                #pragma unroll
                for (int rg = 0; rg < 4; ++rg) {
                    int l0 = (rBase + mi * 32 + 8 * rg) & 2047;
                    float4 t01 = *(const float4*)(tp + l0);
                    float4 t23 = *(const float4*)(tp + l0 + 2);
                    float cs[8] = {t01.x, t01.y, t01.z, t01.w,
                                   t23.x, t23.y, t23.z, t23.w};
                    #pragma unroll
                    for (int q = 0; q < 4; ++q) {
                        int row = rBase + mi * 32 + 8 * rg + q;
                        float cc = cs[2 * q], ss = cs[2 * q + 1];
                        float v  = acc[mi][ni][rg * 4 + q];
                        float pv = __shfl_xor(v, 1);
                        float res = (lane & 1) ? fmaf(v, cc, pv * ss)
                                               : fmaf(v, cc, -pv * ss);
                        O[(size_t)row * DMODEL + col] = f2b(res);
                    }
                }
        }
    }
}

// ---------------------------------------------------------------------------
// Stage 1: 256x256 tile, 512 threads (8 waves, 2M x 4N), BK=64, double-
// buffered 128 KiB LDS, counted vmcnt(2) (one per K-tile).
//
// v5 (ks-slice phases + counted-lgkm fragment pipeline):
//   A phase is now one ks-slice across ALL 8 accumulators:
//     6 ds_read_b128 (a0..a3, b0, b1 at slice ks) -> 8 INDEPENDENT MFMA.
//   Each phase issues the NEXT slice's 6 reads into the alternate register
//   set, then waits lgkmcnt(6) (previous slice complete, next still in
//   flight) -> within-wave LDS/MFMA overlap, zero MFMA dep-chains (each acc
//   touched once per phase, >=100cyc apart). Fragment peak = 48 VGPR
//   (2 sets x 24) -> arch VGPR stays within the 2-waves/SIMD budget.
//   Two block barriers per K-tile (v4): phase-3-exit barrier guards the
//   A0(j+2) overwrite; tile-end barrier (after per-wave vmcnt(2)) guards
//   buf nb's 8 loads before j+1 reads them.
//
// Ledger (per wave, per iter): enter with A0(j+1) in flight (2).
// PH0 +A1(j+1),B0(j+1) (4) -> 6; PH1 +B1(j+1) (2) -> 8; end +A0(j+2) -> 10;
// vmcnt(2) retires the 8 loads of K-tile j+1, leaves A0(j+2).
// Trailing iters stage slightly-OOB columns (still inside d_ws; data never
// consumed). vmcnt(0) drains ALL staging DMA before the epilogue reuses smem.
// ---------------------------------------------------------------------------
__global__ __launch_bounds__(512, 2) void qkv256_kernel(
    const ushort_t* __restrict__ Xb, const ushort_t* __restrict__ Wt,
    const float2* __restrict__ Tab,
    ushort_t* __restrict__ Q, ushort_t* __restrict__ Ko, ushort_t* __restrict__ Vt)
{
    extern __shared__ ushort_t smem[];   // 131072 B
    // byte map: A: buf*32768 + h*16384 ; B: 65536 + buf*32768 + h*16384
    const int tid  = threadIdx.x;
    const int wave = tid >> 6, lane = tid & 63;
    const int wm = wave >> 2, wn = wave & 3;        // 2 x 4 wave grid
    const int l31 = lane & 31, half = lane >> 5;
    const int xl  = l31 & 7;

    // block decode: XCD-bijective swizzle (grid % 8 == 0) + 4x4 supertile
    const int nwg = gridDim.x;
    const int cpx = nwg >> 3;
    const int orig = blockIdx.x;
    const int wg = (orig & 7) * cpx + (orig >> 3);
    const int sup = wg >> 4, inner = wg & 15;
    const int ct = (sup % 3) * 4 + (inner & 3);     // 0..11  (mode = ct>>2)
    const int rt = (sup / 3) * 4 + (inner >> 2);    // row tile
    const int mode = ct >> 2;
    const int row0 = rt << 8;
    const int c0m  = (ct & 3) << 8;                 // col within mode

    const char* gA = (const char*)Xb;                                   // SGPR
    const char* gB = (const char*)(Wt + (size_t)mode * (DMODEL * DMODEL));

    // staging voffsets (bytes): 8 rows per wave, swizzled 16B chunk in row
    const int t8 = tid >> 3;
    const int scol = (((tid & 7) ^ (t8 & 7)) << 3);
    unsigned oA0  = (unsigned)(((row0 + t8) * DMODEL + scol) * 2);
    unsigned oA0b = oA0 + 64  * DMODEL * 2;
    unsigned oA1  = oA0 + 128 * DMODEL * 2;
    unsigned oA1b = oA0 + 192 * DMODEL * 2;
    unsigned oB0  = (unsigned)(((c0m + t8) * DMODEL + scol) * 2);
    unsigned oB0b = oB0 + 64  * DMODEL * 2;
    unsigned oB1  = oB0 + 128 * DMODEL * 2;
    unsigned oB1b = oB0 + 192 * DMODEL * 2;

    char* ldsT = (char*)smem + tid * 16;   // HW uses wave-uniform base + lane*16
    int stg = 0;                           // buf bit for staging (byte offset)

    // ds_read byte addresses (persistent VGPRs, buffer bit toggled ^=32768)
    int vaA[4], vaB[4];
    #pragma unroll
    for (int ks = 0; ks < 4; ++ks) {
        const int swz = (((ks * 2 + half) ^ xl) << 4);
        vaA[ks] = wm * 16384 + l31 * 128 + swz;
        vaB[ks] = 65536 + (wn >> 1) * 16384 + ((wn & 1) * 64 + l31) * 128 + swz;
    }

#define WAITL6 do { asm volatile("s_waitcnt lgkmcnt(6)" ::: "memory"); \
                    __builtin_amdgcn_sched_barrier(0); } while (0)
#define WAITL0 do { asm volatile("s_waitcnt lgkmcnt(0)" ::: "memory"); \
                    __builtin_amdgcn_sched_barrier(0); } while (0)

#define PH_ISSUE(dA0, dA1, dA2, dA3, dB0, dB1, kn)  \
    do {                                             \
        DSR(dA0, vaA[kn], "0");                      \
        DSR(dA1, vaA[kn], "4096");                   \
        DSR(dA2, vaA[kn], "8192");                   \
        DSR(dA3, vaA[kn], "12288");                  \
        DSR(dB0, vaB[kn], "0");                      \
        DSR(dB1, vaB[kn], "4096");                   \
    } while (0)

#define PH_MFMA(A0_, A1_, A2_, A3_, B0_, B1_)                                  \
    do {                                                                       \
        __builtin_amdgcn_s_setprio(1);                                         \
        acc[0][0] = MFMA_B16(as_s8(A0_), as_s8(B0_), acc[0][0], 0, 0, 0);      \
        acc[0][1] = MFMA_B16(as_s8(A0_), as_s8(B1_), acc[0][1], 0, 0, 0);      \
        acc[1][0] = MFMA_B16(as_s8(A1_), as_s8(B0_), acc[1][0], 0, 0, 0);      \
        acc[1][1] = MFMA_B16(as_s8(A1_), as_s8(B1_), acc[1][1], 0, 0, 0);      \
        acc[2][0] = MFMA_B16(as_s8(A2_), as_s8(B0_), acc[2][0], 0, 0, 0);      \
        acc[2][1] = MFMA_B16(as_s8(A2_), as_s8(B1_), acc[2][1], 0, 0, 0);      \
        acc[3][0] = MFMA_B16(as_s8(A3_), as_s8(B0_), acc[3][0], 0, 0, 0);      \
        acc[3][1] = MFMA_B16(as_s8(A3_), as_s8(B1_), acc[3][1], 0, 0, 0);      \
        __builtin_amdgcn_s_setprio(0);                                         \
    } while (0)

    // prologue: K-tile 0 (all 4 half-tiles) + A0 of K-tile 1
    GLOAD_LDS16(gA + oA0,  ldsT);                  GLOAD_LDS16(gA + oA0b, ldsT + 8192);
    GLOAD_LDS16(gA + oA1,  ldsT + 16384);          GLOAD_LDS16(gA + oA1b, ldsT + 16384 + 8192);
    GLOAD_LDS16(gB + oB0,  ldsT + 65536);          GLOAD_LDS16(gB + oB0b, ldsT + 65536 + 8192);
    GLOAD_LDS16(gB + oB1,  ldsT + 65536 + 16384);  GLOAD_LDS16(gB + oB1b, ldsT + 65536 + 16384 + 8192);
    oA0 += 128; oA0b += 128; oA1 += 128; oA1b += 128;
    oB0 += 128; oB0b += 128; oB1 += 128; oB1b += 128;
    GLOAD_LDS16(gA + oA0, ldsT + 32768);           GLOAD_LDS16(gA + oA0b, ldsT + 32768 + 8192);
    oA0 += 128; oA0b += 128;
    asm volatile("s_waitcnt vmcnt(2)" ::: "memory");
    __builtin_amdgcn_s_barrier();

    floatx16 acc[4][2] = {};
    int4v sA0, sA1, sA2, sA3, sB0, sB1;   // fragment set S
    int4v tA0, tA1, tA2, tA3, tB0, tB1;   // fragment set T

    // load slice ks=0 of tile 0 into S (6 outstanding entering the loop)
    PH_ISSUE(sA0, sA1, sA2, sA3, sB0, sB1, 0);

    for (int j = 0; j < 16; ++j) {
        const int nstg = stg ^ 32768;

        // ---- PH0: stage A1,B0(j+1); issue slice1 -> T; wait slice0; MFMA S
        GLOAD_LDS16(gA + oA1,  ldsT + nstg + 16384);
        GLOAD_LDS16(gA + oA1b, ldsT + nstg + 16384 + 8192);
        oA1 += 128; oA1b += 128;
        GLOAD_LDS16(gB + oB0,  ldsT + nstg + 65536);
        GLOAD_LDS16(gB + oB0b, ldsT + nstg + 65536 + 8192);
        oB0 += 128; oB0b += 128;
        PH_ISSUE(tA0, tA1, tA2, tA3, tB0, tB1, 1);
        WAITL6;
        PH_MFMA(sA0, sA1, sA2, sA3, sB0, sB1);

        // ---- PH1: stage B1(j+1); issue slice2 -> S; wait slice1; MFMA T
        GLOAD_LDS16(gB + oB1,  ldsT + nstg + 65536 + 16384);
        GLOAD_LDS16(gB + oB1b, ldsT + nstg + 65536 + 16384 + 8192);
        oB1 += 128; oB1b += 128;
        PH_ISSUE(sA0, sA1, sA2, sA3, sB0, sB1, 2);
        WAITL6;
        PH_MFMA(tA0, tA1, tA2, tA3, tB0, tB1);

        // ---- PH2: issue slice3 -> T; wait slice2; MFMA S
        PH_ISSUE(tA0, tA1, tA2, tA3, tB0, tB1, 3);
        WAITL6;
        PH_MFMA(sA0, sA1, sA2, sA3, sB0, sB1);

        // ---- PH3: wait slice3; MFMA T
        WAITL0;
        PH_MFMA(tA0, tA1, tA2, tA3, tB0, tB1);

        // ---- tile end: all waves' reads of buf b drained (own lgkm above)
        __builtin_amdgcn_s_barrier();
        GLOAD_LDS16(gA + oA0,  ldsT + stg);      // stage A0(j+2) into buf b
        GLOAD_LDS16(gA + oA0b, ldsT + stg + 8192);
        oA0 += 128; oA0b += 128;
        asm volatile("s_waitcnt vmcnt(2)" ::: "memory");  // j+1's 8 loads done
        __builtin_amdgcn_s_barrier();

        stg ^= 32768;
        #pragma unroll
        for (int ks = 0; ks < 4; ++ks) { vaA[ks] ^= 32768; vaB[ks] ^= 32768; }

        // load slice0 of tile j+1 into S (6 in flight entering next iter)
        PH_ISSUE(sA0, sA1, sA2, sA3, sB0, sB1, 0);
    }
    // drain ALL staging DMA before any smem reuse below (latent-race fix)
    asm volatile("s_waitcnt vmcnt(0)" ::: "memory");

    // ------------------------- epilogue -------------------------
    const int rB = row0 + wm * 128 + 4 * half;   // + m*32 + 8*rg + q
    const int cB = c0m + wn * 64 + l31;          // + n*32

    if (mode < 2) {
        ushort_t* O = (mode == 0) ? Q : Ko;
        const float2* Tm = Tab + (size_t)mode * (512 * 2048);
        #pragma unroll
        for (int n = 0; n < 2; ++n) {
            const int col = cB + n * 32;
            const float2* tp = Tm + ((size_t)(col >> 1) << 11);
            #pragma unroll
            for (int m = 0; m < 4; ++m)
                #pragma unroll
                for (int rg = 0; rg < 4; ++rg) {
                    const int row = rB + m * 32 + 8 * rg;
                    const int l0 = row & 2047;
                    float4 t01 = *(const float4*)(tp + l0);
                    float4 t23 = *(const float4*)(tp + l0 + 2);
                    float cs[8] = {t01.x, t01.y, t01.z, t01.w,
                                   t23.x, t23.y, t23.z, t23.w};
                    #pragma unroll
                    for (int q = 0; q < 4; ++q) {
                        float v  = acc[m][n][rg * 4 + q];
                        float pv = __shfl_xor(v, 1);
                        float cc = cs[2 * q], ss = cs[2 * q + 1];
                        float res = (lane & 1) ? fmaf(v, cc, pv * ss)
                                               : fmaf(v, cc, -pv * ss);
                        O[(size_t)(row + q) * DMODEL + col] = f2b(res);
                    }
                }
        }
    } else {
        // V: transpose 256x256 tile via LDS in two 128-col passes
        __syncthreads();
        const int bidx = row0 >> 11, lpos0 = row0 & 2047;
        #pragma unroll
        for (int ph = 0; ph < 2; ++ph) {
            if ((wn >> 1) == ph) {
                const int colL = (wn & 1) * 64 + l31;   // + n*32 -> 0..127
                const int rowL = wm * 128 + 4 * half;   // + m*32 + 8*rg
                #pragma unroll
                for (int m = 0; m < 4; ++m)
                    #pragma unroll
                    for (int n = 0; n < 2; ++n)
                        #pragma unroll
                        for (int rg = 0; rg < 4; ++rg) {
                            short4v pk;
                            pk.x = (short)f2b(acc[m][n][rg * 4 + 0]);
                            pk.y = (short)f2b(acc[m][n][rg * 4 + 1]);
                            pk.z = (short)f2b(acc[m][n][rg * 4 + 2]);
                            pk.w = (short)f2b(acc[m][n][rg * 4 + 3]);
                            *(short4v*)(smem + (size_t)(colL + n * 32) * 264
                                             + rowL + m * 32 + 8 * rg) = pk;
                        }
            }
            __syncthreads();
            const int colV = c0m + ph * 128 + (tid >> 2);
            const int qtr  = tid & 3;
            #pragma unroll
            for (int i = 0; i < 8; ++i) {
                short8 vv = *(const short8*)(smem + (size_t)(tid >> 2) * 264
                                                  + qtr * 64 + i * 8);
                *(short8*)(Vt + (size_t)bidx * (LSEQ * DMODEL)
                              + (size_t)colV * LSEQ + lpos0 + qtr * 64 + i * 8) = vv;
            }
            __syncthreads();
        }
    }
#undef WAITL6
#undef WAITL0
#undef PH_ISSUE
#undef PH_MFMA
}

// ---------------------------------------------------------------------------
// Stage 2: S = Q-hat . K-hat^T (decay pre-folded), banded: only tiles with
// bi-2 <= bj <= bi. 45 tiles per batch.
// ---------------------------------------------------------------------------
__global__ __launch_bounds__(256, 4) void score_kernel(
    const ushort_t* __restrict__ Q, const ushort_t* __restrict__ Kc,
    ushort_t* __restrict__ S)
{
    const int t = blockIdx.x, z = blockIdx.z;
    int bi, bj;
    if (t < 3) { bi = (t > 0); bj = t - (t > 0); }
    else { int u = t - 3; bi = 2 + u / 3; bj = bi - 2 + u % 3; }

    __shared__ ushort_t As[BM * BK], Bs[BN * BK];
    floatx16 acc[2][2] = {};
    const size_t zoff = (size_t)z * (LSEQ * DMODEL);
    gemm_core(Q + zoff, DMODEL, bi * BM, Kc + zoff, DMODEL, bj * BN,
              DMODEL, As, Bs, acc);

    const int wave = threadIdx.x >> 6, lane = threadIdx.x & 63;
    const int wm = wave >> 1, wn = wave & 1;
    const int l31 = lane & 31, half = lane >> 5;
    const int nBase = bi * BM + wm * 64 + 4 * half;
    const int mBase = bj * BN + wn * 64 + l31;
    ushort_t* Sz = S + (size_t)z * LSEQ * LSEQ;
    #pragma unroll
    for (int mi = 0; mi < 2; ++mi)
        #pragma unroll
        for (int ni = 0; ni < 2; ++ni) {
            int m = mBase + ni * 32;
            #pragma unroll
            for (int rg = 0; rg < 4; ++rg)
                #pragma unroll
                for (int q = 0; q < 4; ++q) {
                    int n = nBase + mi * 32 + 8 * rg + q;
                    Sz[(size_t)n * LSEQ + m] =
                        (m <= n) ? f2b(acc[mi][ni][rg * 4 + q]) : (ushort_t)0;
                }
        }
}

// ---------------------------------------------------------------------------
// Stage 3: O = S @ V, banded k-window [max(0,(bi-2)*128), (bi+1)*128).
// ---------------------------------------------------------------------------
__global__ __launch_bounds__(256, 4) void av_kernel(
    const ushort_t* __restrict__ S, const ushort_t* __restrict__ Vt,
    float* __restrict__ Out)
{
    const int bx = blockIdx.x, bi = blockIdx.y, z = blockIdx.z;
    const int kLo = (bi >= 2) ? (bi - 2) * BM : 0;
    const int kW  = (bi + 1) * BM - kLo;
    __shared__ ushort_t As[BM * BK], Bs[BN * BK];
    floatx16 acc[2][2] = {};
    gemm_core(S + (size_t)z * LSEQ * LSEQ + kLo, LSEQ, bi * BM,
              Vt + (size_t)z * (LSEQ * DMODEL) + kLo, LSEQ, bx * BN,
              kW, As, Bs, acc);

    const int wave = threadIdx.x >> 6, lane = threadIdx.x & 63;
    const int wm = wave >> 1, wn = wave & 1;
    const int l31 = lane & 31, half = lane >> 5;
    const int rBase = bi * BM + wm * 64 + 4 * half;
    const int cBase = bx * BN + wn * 64 + l31;
    float* Oz = Out + (size_t)z * (LSEQ * DMODEL);
    #pragma unroll
    for (int mi = 0; mi < 2; ++mi)
        #pragma unroll
        for (int ni = 0; ni < 2; ++ni)
            #pragma unroll
            for (int rg = 0; rg < 4; ++rg)
                #pragma unroll
                for (int q = 0; q < 4; ++q)
                    Oz[(size_t)(rBase + mi * 32 + 8 * rg + q) * DMODEL
                       + cBase + ni * 32] = acc[mi][ni][rg * 4 + q];
}

// ---------------------------------------------------------------------------
extern "C" void kernel_launch(void* const* d_in, const int* in_sizes, int n_in,
                              void* d_out, int out_size, void* d_ws, size_t ws_size,
                              hipStream_t stream)
{
    const float* X  = (const float*)d_in[0];
    const float* Wq = (const float*)d_in[1];
    const float* Wk = (const float*)d_in[2];
    const float* Wv = (const float*)d_in[3];
    float* out = (float*)d_out;

    const size_t LH  = (size_t)LSEQ * DMODEL;
    const size_t WSZ = (size_t)DMODEL * DMODEL;
    const size_t SSZ = (size_t)LSEQ * LSEQ;
    const size_t TABN = (size_t)2 * 512 * 2048;

    size_t need4 = TABN * 8 + 2 * (3 * WSZ + 4 * (4 * LH + SSZ));
    const int bs = (ws_size >= need4) ? 4 : 1;

    float2* Tab = (float2*)d_ws;
    ushort_t* ws16 = (ushort_t*)(Tab + TABN);
    ushort_t* Wt = ws16;
    ushort_t* Xb = Wt + 3 * WSZ;
    ushort_t* Q  = Xb + (size_t)bs * LH;
    ushort_t* Kb = Q  + (size_t)bs * LH;
    ushort_t* Vt = Kb + (size_t)bs * LH;
    ushort_t* S  = Vt + (size_t)bs * LH;

    // one-time: allow 128 KiB dynamic LDS for the pipelined QKV kernel
    static int qkv256_ok = -1;
    if (qkv256_ok < 0) {
        hipError_t e = hipFuncSetAttribute(
            reinterpret_cast<const void*>(qkv256_kernel),
            hipFuncAttributeMaxDynamicSharedMemorySize, 131072);
        qkv256_ok = (e == hipSuccess) ? 1 : 0;
    }

    xpos_table_kernel<<<dim3(TABN / 256), 256, 0, stream>>>(Tab);
    wtrans_kernel<<<dim3(32, 32, 3), 256, 0, stream>>>(Wq, Wk, Wv, Wt);

    for (int p = 0; p < 4 / bs; ++p) {
        const float* Xp = X + (size_t)p * bs * LH;
        cast_x_kernel<<<dim3(bs * 2048), 256, 0, stream>>>(
            (const float4*)Xp, (short4v*)Xb, bs * (int)(LH / 4));
        if (qkv256_ok)
            qkv256_kernel<<<dim3(96 * bs), 512, 131072, stream>>>(
                Xb, Wt, Tab, Q, Kb, Vt);
        else
            qkv_kernel<<<dim3(24 * bs * 16), 256, 0, stream>>>(
                Xb, Wt, Tab, Q, Kb, Vt);
        score_kernel<<<dim3(45, 1, bs), 256, 0, stream>>>(Q, Kb, S);
        av_kernel<<<dim3(8, 16, bs), 256, 0, stream>>>(S, Vt,
            out + (size_t)p * bs * LH);
    }
}